// Round 4
// baseline (1579.940 us; speedup 1.0000x reference)
//
#include <hip/hip_runtime.h>
#include <math.h>

#define T_LEN 4096
#define C_LEN 256
#define B_LEN 16

typedef float v2f __attribute__((ext_vector_type(2)));

__device__ __forceinline__ v2f splat2(float s) { return (v2f){s, s}; }
__device__ __forceinline__ v2f fma2(v2f a, v2f b, v2f c) {
    return __builtin_elementwise_fma(a, b, c);   // -> v_pk_fma_f32 on gfx950
}

// ---------------------------------------------------------------------------
// Compile-time Gaussian kernel bank (matches numpy: exp(-0.5*(j/s)^2), trunc
// at r=int(4*s), normalized by sum+1e-12). Values become instruction literals.
// ---------------------------------------------------------------------------
constexpr double cexp(double x) {
    double y = x * (1.0 / 1024.0);
    double t = 1.0, term = 1.0;
    for (int i = 1; i <= 12; ++i) { term *= y / i; t += term; }
    for (int i = 0; i < 10; ++i) t = t * t;   // ^1024
    return t;
}

constexpr int RAD[5] = {10, 16, 24, 36, 56};

struct Bank { float g[5][57]; };

constexpr Bank make_bank() {
    Bank b{};
    const double sig[5] = {2.5, 4.0, 6.0, 9.0, 14.0};
    for (int k = 0; k < 5; ++k) {
        double w[57] = {};
        for (int j = 0; j <= RAD[k]; ++j)
            w[j] = cexp(-0.5 * (double)(j * j) / (sig[k] * sig[k]));
        double s = w[0];
        for (int j = 1; j <= RAD[k]; ++j) s += 2.0 * w[j];
        s += 1e-12;
        for (int j = 0; j <= RAD[k]; ++j) b.g[k][j] = (float)(w[j] / s);
    }
    return b;
}

constexpr Bank BANK = make_bank();

#define LOG2E 1.4426950408889634f

__device__ __forceinline__ float fast_exp2(float x) {
#if __has_builtin(__builtin_amdgcn_exp2f)
    return __builtin_amdgcn_exp2f(x);
#else
    return __expf(x * 0.6931471805599453f);
#endif
}

// ---------------------------------------------------------------------------
// Fast GELU (tanh form), PACKED pair version: VALU part is 5 pk-ops for two
// gelus; the 2x(exp2+rcp) run on the quarter-rate trans pipe, which is
// hidden under regular-VALU issue with >=2 resident waves (R3 lesson).
// ---------------------------------------------------------------------------
__device__ __forceinline__ v2f gelu2(v2f v) {
    const float c1 = (float)(-2.0 * 0.7978845608028654 * 1.4426950408889634);
    const float c2 = c1 * 0.044715f;
    v2f v2 = v * v;                        // pk_mul
    v2f t  = fma2(splat2(c2), v2, splat2(c1));
    v2f z  = v * t;                        // pk_mul
    v2f e  = {fast_exp2(z.x), fast_exp2(z.y)};
    v2f d  = e + 1.0f;                     // pk_add
    v2f r  = {__builtin_amdgcn_rcpf(d.x), __builtin_amdgcn_rcpf(d.y)};
    return v * r;                          // pk_mul
}

__device__ __forceinline__ float ldz(const float* __restrict__ xb, int tt) {
    if (tt < 0 || tt >= T_LEN) return 0.0f;
    return xb[tt * C_LEN];
}

// ---------------------------------------------------------------------------
// Per-thread worker: one channel c, 4 consecutive t starting at t0, processed
// as two packed pairs (m0,m1) and (m2,m3). CHECKED handles series edges.
// ---------------------------------------------------------------------------
template <bool CHECKED>
__device__ __forceinline__ void work(const float* __restrict__ x,
                                     float* __restrict__ out,
                                     const float (*__restrict__ wle)[8],
                                     const float* __restrict__ w2e,
                                     const float* __restrict__ b2l,
                                     int b, int t0, int c) {
    const float* xb = x + (size_t)b * T_LEN * C_LEN + c;  // index by t*C_LEN

    // ---- pooling window values: x[t0-7 .. t0+11] (reflect at edges) ----
    float v[19];
#pragma unroll
    for (int i = 0; i < 19; ++i) {
        int tt = t0 - 7 + i;
        if (CHECKED) {
            tt = (tt < 0) ? -tt : tt;
            tt = (tt >= T_LEN) ? (2 * T_LEN - 2 - tt) : tt;
        }
        v[i] = xb[tt * C_LEN];
    }

    float mean[4], var[4], xc[4];
    {
        float s = 0.f, q = 0.f;
#pragma unroll
        for (int i = 0; i < 16; ++i) { s += v[i]; q = fmaf(v[i], v[i], q); }
#pragma unroll
        for (int m = 0; m < 4; ++m) {
            if (m > 0) {
                float nw = v[15 + m], od = v[m - 1];
                s = s + nw - od;
                q = fmaf(nw, nw, fmaf(od, -od, q));
            }
            mean[m] = s * 0.0625f;
            float m2 = q * 0.0625f;
            float vv = fmaf(-mean[m], mean[m], m2);
            var[m] = vv > 0.f ? vv : 0.f;
            xc[m]  = v[7 + m];   // x[t0+m] (always in range -> reflect is identity)
        }
    }

    v2f meanP[2] = {{mean[0], mean[1]}, {mean[2], mean[3]}};
    v2f varP [2] = {{var [0], var [1]}, {var [2], var [3]}};
    v2f xcP  [2] = {{xc  [0], xc  [1]}, {xc  [2], xc  [3]}};

    // ---- 5 Gaussian convs, symmetric-pair register sliding windows ----
    v2f accP[5][2];
#pragma unroll
    for (int k = 0; k < 5; ++k) {
        v2f g0 = splat2(BANK.g[k][0]);
        accP[k][0] = g0 * xcP[0];
        accP[k][1] = g0 * xcP[1];
    }

    float F[4], Bw[4];
    if (CHECKED) {
        F[1] = ldz(xb, t0 + 1); F[2] = ldz(xb, t0 + 2);
        F[3] = ldz(xb, t0 + 3); F[0] = ldz(xb, t0 + 4);
        Bw[3] = ldz(xb, t0 - 1); Bw[0] = ldz(xb, t0);
        Bw[1] = ldz(xb, t0 + 1); Bw[2] = ldz(xb, t0 + 2);
    } else {
        F[1] = v[8]; F[2] = v[9]; F[3] = v[10]; F[0] = v[11];
        Bw[3] = v[6]; Bw[0] = v[7]; Bw[1] = v[8]; Bw[2] = v[9];
    }

#pragma unroll
    for (int j = 1; j <= 56; ++j) {
        float sm0 = F[(j + 0) & 3] + Bw[(0 - j) & 3];
        float sm1 = F[(j + 1) & 3] + Bw[(1 - j) & 3];
        float sm2 = F[(j + 2) & 3] + Bw[(2 - j) & 3];
        float sm3 = F[(j + 3) & 3] + Bw[(3 - j) & 3];
        v2f smA = {sm0, sm1};
        v2f smB = {sm2, sm3};
#pragma unroll
        for (int k = 0; k < 5; ++k) {
            if (j <= RAD[k]) {
                v2f g = splat2(BANK.g[k][j]);
                accP[k][0] = fma2(g, smA, accP[k][0]);
                accP[k][1] = fma2(g, smB, accP[k][1]);
            }
        }
        if (j < 56) {
            if (CHECKED) {
                F[j & 3]        = ldz(xb, t0 + j + 4);
                Bw[(3 - j) & 3] = ldz(xb, t0 - j - 1);
            } else {
                F[j & 3]        = (j <= 7) ? v[j + 11] : xb[(t0 + j + 4) * C_LEN];
                Bw[(3 - j) & 3] = (j <= 6) ? v[6 - j]  : xb[(t0 - j - 1) * C_LEN];
            }
        }
    }

    // ---- conditioner MLP: 3 -> 32 (packed GELU) -> 5 logits (pre-scaled by
    // log2e at weight-staging time so softmax uses raw v_exp_f32) ----
    v2f lgP[5][2];
#pragma unroll
    for (int k = 0; k < 5; ++k) {
        v2f bk = splat2(b2l[k]);
        lgP[k][0] = bk;
        lgP[k][1] = bk;
    }

#pragma unroll 2
    for (int i = 0; i < 32; ++i) {
        float4 wa = *(const float4*)&wle[i][0];  // w1_0, w1_1, w1_2, b1
        float4 wb = *(const float4*)&wle[i][4];  // w2_0..w2_3  (x log2e)
        float w24 = w2e[i];                      // w2_4        (x log2e)
#pragma unroll
        for (int p = 0; p < 2; ++p) {
            v2f pre = fma2(splat2(wa.x), meanP[p],
                      fma2(splat2(wa.y), varP[p],
                      fma2(splat2(wa.z), xcP[p], splat2(wa.w))));
            v2f h = gelu2(pre);
            lgP[0][p] = fma2(h, splat2(wb.x), lgP[0][p]);
            lgP[1][p] = fma2(h, splat2(wb.y), lgP[1][p]);
            lgP[2][p] = fma2(h, splat2(wb.z), lgP[2][p]);
            lgP[3][p] = fma2(h, splat2(wb.w), lgP[3][p]);
            lgP[4][p] = fma2(h, splat2(w24 ), lgP[4][p]);
        }
    }

    // ---- softmax over K=5 (logits already x log2e; bounded, no max needed —
    // validated by R3 run) + mixture, store ----
#pragma unroll
    for (int p = 0; p < 2; ++p) {
        v2f e0 = {fast_exp2(lgP[0][p].x), fast_exp2(lgP[0][p].y)};
        v2f e1 = {fast_exp2(lgP[1][p].x), fast_exp2(lgP[1][p].y)};
        v2f e2 = {fast_exp2(lgP[2][p].x), fast_exp2(lgP[2][p].y)};
        v2f e3 = {fast_exp2(lgP[3][p].x), fast_exp2(lgP[3][p].y)};
        v2f e4 = {fast_exp2(lgP[4][p].x), fast_exp2(lgP[4][p].y)};
        v2f den = ((e0 + e1) + (e2 + e3)) + e4;
        v2f num = e0 * accP[0][p];
        num = fma2(e1, accP[1][p], num);
        num = fma2(e2, accP[2][p], num);
        num = fma2(e3, accP[3][p], num);
        num = fma2(e4, accP[4][p], num);
        v2f r = {__builtin_amdgcn_rcpf(den.x), __builtin_amdgcn_rcpf(den.y)};
        v2f o = num * r;
        out[((size_t)b * T_LEN + t0 + 2 * p + 0) * C_LEN + c] = o.x;
        out[((size_t)b * T_LEN + t0 + 2 * p + 1) * C_LEN + c] = o.y;
    }
}

// ---------------------------------------------------------------------------
// Single fused kernel: boundary chunks (28/1024 per b) take the CHECKED path,
// block-uniform branch. __launch_bounds__(256,4) pins VGPR<=128: R3 showed
// the occupancy cliff at VGPR>128 costs ~50%.
// ---------------------------------------------------------------------------
__global__ __launch_bounds__(256, 4) void agt_fused(
    const float* __restrict__ x, const float* __restrict__ W1,
    const float* __restrict__ b1, const float* __restrict__ W2,
    const float* __restrict__ b2, float* __restrict__ out) {
    __shared__ __align__(16) float wle[32][8];
    __shared__ float w2e[32];
    __shared__ float b2l[5];
    {
        int tid = threadIdx.x;
        if (tid < 32) {
            wle[tid][0] = W1[tid];
            wle[tid][1] = W1[32 + tid];
            wle[tid][2] = W1[64 + tid];
            wle[tid][3] = b1[tid];
            wle[tid][4] = W2[tid * 5 + 0] * LOG2E;
            wle[tid][5] = W2[tid * 5 + 1] * LOG2E;
            wle[tid][6] = W2[tid * 5 + 2] * LOG2E;
            wle[tid][7] = W2[tid * 5 + 3] * LOG2E;
            w2e[tid]    = W2[tid * 5 + 4] * LOG2E;
            if (tid < 5) b2l[tid] = b2[tid] * LOG2E;
        }
        __syncthreads();
    }
    int b     = blockIdx.x >> 10;        // 1024 chunks per batch
    int chunk = blockIdx.x & 1023;
    int t0    = chunk * 4;
    if (chunk >= 14 && chunk < 1010)
        work<false>(x, out, wle, w2e, b2l, b, t0, threadIdx.x);
    else
        work<true>(x, out, wle, w2e, b2l, b, t0, threadIdx.x);
}

extern "C" void kernel_launch(void* const* d_in, const int* in_sizes, int n_in,
                              void* d_out, int out_size, void* d_ws, size_t ws_size,
                              hipStream_t stream) {
    const float* x  = (const float*)d_in[0];
    const float* W1 = (const float*)d_in[1];
    const float* b1 = (const float*)d_in[2];
    const float* W2 = (const float*)d_in[3];
    const float* b2 = (const float*)d_in[4];
    float* out = (float*)d_out;

    (void)in_sizes; (void)n_in; (void)d_ws; (void)ws_size; (void)out_size;

    agt_fused<<<dim3(B_LEN * 1024), dim3(256), 0, stream>>>(x, W1, b1, W2, b2, out);
}